// Round 1
// baseline (288.738 us; speedup 1.0000x reference)
//
#include <hip/hip_runtime.h>

#define T_STEPS 512
#define NF 16
#define PF 8   // prefetch depth in time steps

// ---- fast device math (fp32, ~1ulp) ----
__device__ __forceinline__ float rcp_fast(float x) {
    return __builtin_amdgcn_rcpf(x);
}

// broadcast quad-lane S's value to all 4 lanes of the quad (pure VALU DPP)
template <int S>
__device__ __forceinline__ float qbcast(float v) {
    return __int_as_float(
        __builtin_amdgcn_mov_dpp(__float_as_int(v), S * 0x55, 0xF, 0xF, true));
}

// sum across the quad (butterfly via quad_perm)
__device__ __forceinline__ float qsum(float p) {
    p += __int_as_float(__builtin_amdgcn_mov_dpp(__float_as_int(p), 0xB1, 0xF, 0xF, true)); // [1,0,3,2]
    p += __int_as_float(__builtin_amdgcn_mov_dpp(__float_as_int(p), 0x4E, 0xF, 0xF, true)); // [2,3,0,1]
    return p;
}

__device__ __forceinline__ float sigmoid_f(float s) {
    // 1 / (1 + e^-s)
    return rcp_fast(1.0f + __expf(-s));
}

__device__ __forceinline__ float tanh_f(float u) {
    // 1 - 2/(e^{2u}+1)
    return fmaf(-2.0f, rcp_fast(__expf(2.0f * u) + 1.0f), 1.0f);
}

// One wave (64 lanes) = 16 batch rows; quad lane j owns hidden unit j and
// gate rows {j, 4+j, 8+j}. block=64 so each wave is its own workgroup ->
// 256 blocks spread over 256 CUs (1 wave/CU, all CUs busy).
__global__ __launch_bounds__(64, 1) void gru_fused_kernel(
    const float* __restrict__ x,     // [B, T, 16]
    const float* __restrict__ w_ih,  // [12, 16]
    const float* __restrict__ w_hh,  // [12, 4]
    const float* __restrict__ b_ih,  // [12]
    const float* __restrict__ b_hh,  // [12]
    const float* __restrict__ fc_w,  // [1, 4]
    const float* __restrict__ fc_b,  // [1]
    float* __restrict__ out)         // [B]
{
    const int lane = threadIdx.x;        // 0..63
    const int q    = lane >> 2;          // quad index within wave (0..15)
    const int j    = lane & 3;           // hidden unit owned by this lane
    const int b    = blockIdx.x * 16 + q;

    // ---- per-lane weights into registers (one-time, tiny) ----
    float wr[NF], wz[NF], wn[NF];
#pragma unroll
    for (int f = 0; f < NF; ++f) {
        wr[f] = w_ih[(0 + j) * NF + f];
        wz[f] = w_ih[(4 + j) * NF + f];
        wn[f] = w_ih[(8 + j) * NF + f];
    }
    float ur[4], uz[4], un[4];
#pragma unroll
    for (int k = 0; k < 4; ++k) {
        ur[k] = w_hh[(0 + j) * 4 + k];
        uz[k] = w_hh[(4 + j) * 4 + k];
        un[k] = w_hh[(8 + j) * 4 + k];
    }
    const float br  = b_ih[0 + j] + b_hh[0 + j];  // r-gate total bias
    const float bz  = b_ih[4 + j] + b_hh[4 + j];  // z-gate total bias
    const float bin = b_ih[8 + j];                // n-gate input bias (kept separate!)
    const float bhn = b_hh[8 + j];                // n-gate hidden bias (inside r* term)

    // x[b][t][4j..4j+3] as float4: index (b*T + t)*4 + j
    const float4* xp = (const float4*)x + ((size_t)b * T_STEPS) * 4 + j;

    // ---- rolling register prefetch, PF steps deep ----
    float4 buf[PF];
#pragma unroll
    for (int i = 0; i < PF; ++i) buf[i] = xp[(size_t)i * 4];

    float h = 0.0f;

    for (int t0 = 0; t0 < T_STEPS; t0 += PF) {
#pragma unroll
        for (int u = 0; u < PF; ++u) {
            float4 xq = buf[u];
            int tn = t0 + u + PF;          // uniform branch: prefetch next tile
            if (tn < T_STEPS) buf[u] = xp[(size_t)tn * 4];

            // ---- x projection: gi = W_ih[x-rows] . x + bias ----
            float gr = br, gz = bz, gn = bin;
#define XBLK(S)                                                              \
            {                                                                \
                float x0 = qbcast<S>(xq.x), x1 = qbcast<S>(xq.y);            \
                float x2 = qbcast<S>(xq.z), x3 = qbcast<S>(xq.w);            \
                gr = fmaf(wr[4*S+0], x0, gr); gr = fmaf(wr[4*S+1], x1, gr);  \
                gr = fmaf(wr[4*S+2], x2, gr); gr = fmaf(wr[4*S+3], x3, gr);  \
                gz = fmaf(wz[4*S+0], x0, gz); gz = fmaf(wz[4*S+1], x1, gz);  \
                gz = fmaf(wz[4*S+2], x2, gz); gz = fmaf(wz[4*S+3], x3, gz);  \
                gn = fmaf(wn[4*S+0], x0, gn); gn = fmaf(wn[4*S+1], x1, gn);  \
                gn = fmaf(wn[4*S+2], x2, gn); gn = fmaf(wn[4*S+3], x3, gn);  \
            }
            XBLK(0) XBLK(1) XBLK(2) XBLK(3)
#undef XBLK

            // ---- recurrent part: gh = W_hh . h ----
            float h0 = qbcast<0>(h), h1 = qbcast<1>(h);
            float h2 = qbcast<2>(h), h3 = qbcast<3>(h);
            gr = fmaf(ur[0], h0, gr); gr = fmaf(ur[1], h1, gr);
            gr = fmaf(ur[2], h2, gr); gr = fmaf(ur[3], h3, gr);
            gz = fmaf(uz[0], h0, gz); gz = fmaf(uz[1], h1, gz);
            gz = fmaf(uz[2], h2, gz); gz = fmaf(uz[3], h3, gz);
            float ghn = bhn;
            ghn = fmaf(un[0], h0, ghn); ghn = fmaf(un[1], h1, ghn);
            ghn = fmaf(un[2], h2, ghn); ghn = fmaf(un[3], h3, ghn);

            // ---- gates (PyTorch GRU order r, z, n) ----
            float r = sigmoid_f(gr);
            float z = sigmoid_f(gz);
            float n = tanh_f(fmaf(r, ghn, gn));
            // h = (1-z)*n + z*h  ==  n + z*(h - n)
            h = fmaf(z, h - n, n);
        }
    }

    // ---- epilogue: out[b] = h . fc_w + fc_b ----
    float p = h * fc_w[j];
    p = qsum(p);
    if (j == 0) out[b] = p + fc_b[0];
}

extern "C" void kernel_launch(void* const* d_in, const int* in_sizes, int n_in,
                              void* d_out, int out_size, void* d_ws, size_t ws_size,
                              hipStream_t stream) {
    const float* x    = (const float*)d_in[0];
    const float* w_ih = (const float*)d_in[1];
    const float* w_hh = (const float*)d_in[2];
    const float* b_ih = (const float*)d_in[3];
    const float* b_hh = (const float*)d_in[4];
    const float* fc_w = (const float*)d_in[5];
    const float* fc_b = (const float*)d_in[6];
    float* out = (float*)d_out;

    const int B = out_size;          // 4096
    const int grid = B / 16;         // 16 batch rows per 64-thread block (one wave)
    gru_fused_kernel<<<grid, 64, 0, stream>>>(x, w_ih, w_hh, b_ih, b_hh, fc_w, fc_b, out);
}